// Round 9
// baseline (204.413 us; speedup 1.0000x reference)
//
#include <hip/hip_runtime.h>
#include <hip/hip_bf16.h>
#include <stdint.h>

#define E_EDGES   800000
#define N_NODES_C 50000
#define NG        64
#define DD        128     // NODE_DIM == INSTR_DIM
#define HH        256     // HIDDEN_DIM
#define KDIM      384     // 2*128 + 128
#define CHUNKS    196     // ceil(50000/256)
#define SCAT_STRIDE 200192  // 391 blocks * 512 threads

typedef __bf16 bf16x8 __attribute__((ext_vector_type(8)));
typedef __bf16 bf16x4 __attribute__((ext_vector_type(4)));
typedef float  f32x4  __attribute__((ext_vector_type(4)));
typedef uint32_t u32x4 __attribute__((ext_vector_type(4)));

__device__ __forceinline__ void gld16(const void* g, void* l) {
  __builtin_amdgcn_global_load_lds(
      (__attribute__((address_space(1))) void*)g,
      (__attribute__((address_space(3))) void*)l, 16, 0, 0);
}

__device__ __forceinline__ float bf_hi(uint32_t u) { return __uint_as_float(u & 0xffff0000u); }
__device__ __forceinline__ float bf_lo(uint32_t u) { return __uint_as_float(u << 16); }

// ---------------- prep kernel: w1pt transpose + r2 + edge-src histogram -----
// blocks [0,256): w1pt[n][k] (512x128 bf16)
// blocks [256,320): r2[g][c] = instr[g] @ W1c + b1
// blocks [320, 320+3125): histogram of ei src into cnt
#define PREP_W1_BLKS  256
#define PREP_R2_BLKS  64
#define PREP_HIST_BLKS 3125

template <int HIST>
__global__ void k_prep(const float* __restrict__ w1, const float* __restrict__ instr,
                       const float* __restrict__ b1, const int* __restrict__ ei,
                       __bf16* __restrict__ w1pt, float* __restrict__ r2,
                       int* __restrict__ cnt) {
  __shared__ float ins[DD];
  const int bid = blockIdx.x;
  const int tid = threadIdx.x;
  if (bid < PREP_W1_BLKS) {
    int idx = bid * 256 + tid;                 // 512*128 = 65536
    int n = idx >> 7;
    int k = idx & 127;
    float v = (n < 256) ? w1[k * HH + n] : w1[(128 + k) * HH + (n - 256)];
    w1pt[n * 128 + k] = (__bf16)v;
  } else if (bid < PREP_W1_BLKS + PREP_R2_BLKS) {
    int g = bid - PREP_W1_BLKS;
    int c = tid;
    if (c < DD) ins[c] = instr[g * DD + c];
    __syncthreads();
    float sum = b1[c];
#pragma unroll 8
    for (int k = 0; k < DD; ++k) sum += ins[k] * w1[(256 + k) * HH + c];
    r2[g * HH + c] = sum;
  } else if (HIST) {
    int e = (bid - (PREP_W1_BLKS + PREP_R2_BLKS)) * 256 + tid;
    if (e < E_EDGES) atomicAdd(&cnt[ei[e]], 1);
  }
}

// ---------------- hierarchical counting-sort scan (r7-proven) ----------------
__global__ void k_scan1(int* __restrict__ cnt, int* __restrict__ pref) {
  __shared__ int ts[256];
  const int t = threadIdx.x;
  const int i = blockIdx.x * 256 + t;
  int v = (i < N_NODES_C) ? cnt[i] : 0;
  ts[t] = v;
  __syncthreads();
  for (int off = 1; off < 256; off <<= 1) {
    int u = (t >= off) ? ts[t - off] : 0;
    __syncthreads();
    ts[t] += u;
    __syncthreads();
  }
  if (i < N_NODES_C) cnt[i] = ts[t] - v;        // exclusive within chunk
  if (t == 255) pref[blockIdx.x] = ts[255];     // chunk total
}

__global__ void k_scan2(int* __restrict__ pref) {
  __shared__ int ts[256];
  const int t = threadIdx.x;
  int v = (t < CHUNKS) ? pref[t] : 0;
  ts[t] = v;
  __syncthreads();
  for (int off = 1; off < 256; off <<= 1) {
    int u = (t >= off) ? ts[t - off] : 0;
    __syncthreads();
    ts[t] += u;
    __syncthreads();
  }
  if (t < CHUNKS) pref[t] = ts[t] - v;          // exclusive chunk offsets
}

// ---------------- phase 1: node GEMM (+ fused edge scatter slice) ----------
// y in {0,1}: PQ = x @ [W1a | W1b], P-half += r2, all scaled by log2(e).
// y == 2   : counting-sort scatter (independent of the GEMM slices).
__launch_bounds__(512, 4)
__global__ void k_nodegemm(const float* __restrict__ x,
                           const __bf16* __restrict__ w1pt,
                           const int*   __restrict__ batch,
                           const float* __restrict__ r2,
                           __bf16* __restrict__ pq,
                           const int*  __restrict__ ei,
                           int*  __restrict__ cnt,
                           const int* __restrict__ pref,
                           int2* __restrict__ sde)
{
  if (blockIdx.y == 2) {
    // scatter: slot = pref[chunk] + (in-chunk base & arrival idx via atomic).
    // Slot races are benign: out[e] depends only on edge e's own data.
    int idx = blockIdx.x * 512 + threadIdx.x;
#pragma unroll
    for (int j = 0; j < 4; ++j) {
      int e = idx + j * SCAT_STRIDE;
      if (e < E_EDGES) {
        int s = ei[e];
        int d = ei[E_EDGES + e];
        int slot = pref[s >> 8] + atomicAdd(&cnt[s], 1);
        sde[slot] = make_int2(s | (d << 16), e);
      }
    }
    return;
  }

  __shared__ __align__(16) char smem[16384 + 32768];
  char* As = smem;             // 2 x [128 rows][32k] bf16, swizzled 16B slots
  char* Bs = smem + 16384;     // 2 x [256 cols][32k] bf16

  const int tid  = threadIdx.x;
  const int lane = tid & 63;
  const int wid  = tid >> 6;
  const int rowbase = blockIdx.x * 128;
  const int nt      = blockIdx.y;          // 0/1 -> cols [0,256) / [256,512)

  const int arow  = tid >> 2;
  const int aslot = tid & 3;
  const int akap  = aslot ^ ((arow >> 1) & 3);
  int gr = rowbase + arow; if (gr >= N_NODES_C) gr = N_NODES_C - 1;
  const float* aptr = x + (size_t)gr * DD + akap * 8;

  const char* bptr[2];
#pragma unroll
  for (int it = 0; it < 2; ++it) {
    int j2 = tid + it * 512;
    int n  = j2 >> 2;
    int bk = (j2 & 3) ^ ((n >> 1) & 3);
    bptr[it] = (const char*)w1pt + (size_t)(nt * 256 + n) * 256 + bk * 16;
  }

  char* ldsB = Bs + wid * 1024;

  auto stage = [&](int cur, int kk) {
    gld16(bptr[0] + kk * 64, ldsB + cur * 16384);
    gld16(bptr[1] + kk * 64, ldsB + cur * 16384 + 8192);
    const float* gf = aptr + kk * 32;
    float4 v0 = *(const float4*)gf;
    float4 v1 = *(const float4*)(gf + 4);
    bf16x8 bv;
    bv[0] = (__bf16)v0.x; bv[1] = (__bf16)v0.y; bv[2] = (__bf16)v0.z; bv[3] = (__bf16)v0.w;
    bv[4] = (__bf16)v1.x; bv[5] = (__bf16)v1.y; bv[6] = (__bf16)v1.z; bv[7] = (__bf16)v1.w;
    *(bf16x8*)(As + cur * 8192 + tid * 16) = bv;
  };

  const int wm    = wid >> 2;
  const int wn    = wid & 3;
  const int l15   = lane & 15;
  const int kap_r = (lane >> 4) ^ ((l15 >> 1) & 3);
  const int aoff  = wm * 4096 + l15 * 64 + kap_r * 16;
  const int boff  = wn * 4096 + l15 * 64 + kap_r * 16;

  f32x4 acc[4][4];
#pragma unroll
  for (int mi = 0; mi < 4; ++mi)
#pragma unroll
    for (int ni = 0; ni < 4; ++ni)
      acc[mi][ni] = f32x4{0.f, 0.f, 0.f, 0.f};

  stage(0, 0);

  for (int kk = 0; kk < 4; ++kk) {
    const int cur = kk & 1;
    __syncthreads();
    if (kk + 1 < 4) stage(cur ^ 1, kk + 1);

    const char* pA = As + cur * 8192;
    const char* pB = Bs + cur * 16384;
    bf16x8 av[4], bv[4];
#pragma unroll
    for (int mi = 0; mi < 4; ++mi) av[mi] = *(const bf16x8*)(pA + aoff + mi * 1024);
#pragma unroll
    for (int ni = 0; ni < 4; ++ni) bv[ni] = *(const bf16x8*)(pB + boff + ni * 1024);
#pragma unroll
    for (int mi = 0; mi < 4; ++mi)
#pragma unroll
      for (int ni = 0; ni < 4; ++ni)
        acc[mi][ni] = __builtin_amdgcn_mfma_f32_16x16x32_bf16(av[mi], bv[ni], acc[mi][ni], 0, 0, 0);
  }

  const int rg = lane >> 4;
  const bool fold = (nt == 0);
  const float L2E = 1.44269504f;
#pragma unroll
  for (int mi = 0; mi < 4; ++mi) {
    int row = rowbase + wm * 64 + mi * 16 + rg * 4;
#pragma unroll
    for (int r = 0; r < 4; ++r) {
      int rr = row + r;
      if (rr < N_NODES_C) {
        float addv[4] = {0.f, 0.f, 0.f, 0.f};
        if (fold) {
          int g = batch[rr];
          const float* r2row = r2 + g * HH + wn * 64 + l15;
#pragma unroll
          for (int ni = 0; ni < 4; ++ni) addv[ni] = r2row[ni * 16];
        }
        size_t base = (size_t)rr * 512 + nt * 256 + wn * 64 + l15;
#pragma unroll
        for (int ni = 0; ni < 4; ++ni)
          pq[base + ni * 16] = (__bf16)((acc[mi][ni][r] + addv[ni]) * L2E);
      }
    }
  }
}

// ---------------- shared silu-dot core (PQ prescaled by log2e, w2 by ln2) ---
__device__ __forceinline__ void silu_dot2(const u32x4& p, const u32x4& q,
                                          const float* w2r, float& sum) {
#pragma unroll
  for (int k = 0; k < 4; ++k) {
    float va = bf_lo(p[k]) + bf_lo(q[k]);      // v' = 1.4427*v
    float vb = bf_hi(p[k]) + bf_hi(q[k]);
    float ta = __builtin_amdgcn_exp2f(-va);    // e^-v
    float tb = __builtin_amdgcn_exp2f(-vb);
    float da = 1.f + ta, db = 1.f + tb;
    float rc = __builtin_amdgcn_rcpf(da * db);
    sum += (va * w2r[2 * k]) * (rc * db) + (vb * w2r[2 * k + 1]) * (rc * da);
  }
}

// ---------------- phase 2: src-sorted edge gather + silu + dot(w2) ----------
// r7-proven: 87 us, FETCH 206 MB, absmax 0.0039. Unchanged.
__launch_bounds__(256, 8)
__global__ void k_edge2(const __bf16* __restrict__ pq,
                        const int2*  __restrict__ sde,
                        const float* __restrict__ w2,
                        const float* __restrict__ b2,
                        float* __restrict__ out)
{
  const int tid  = threadIdx.x;
  const int lane = tid & 63;
  const int wid  = tid >> 6;
  const int half = lane >> 5;
  const int l    = lane & 31;
  const int c0   = l * 8;
  const float LN2 = 0.69314718f;

  float w2r[8];
  {
    float4 a = *(const float4*)(w2 + c0);
    float4 b = *(const float4*)(w2 + c0 + 4);
    w2r[0]=a.x*LN2; w2r[1]=a.y*LN2; w2r[2]=a.z*LN2; w2r[3]=a.w*LN2;
    w2r[4]=b.x*LN2; w2r[5]=b.y*LN2; w2r[6]=b.z*LN2; w2r[7]=b.w*LN2;
  }
  const float bb = b2[0];

  for (int sl = blockIdx.x * 16 + (wid * 2 + half) * 2; sl < E_EDGES; sl += gridDim.x * 16) {
    int4 t = *(const int4*)(sde + sl);       // 2 packed edges (sl even)
    int s0 = t.x & 0xFFFF, d0 = ((unsigned)t.x) >> 16, e0 = t.y;
    int s1 = t.z & 0xFFFF, d1 = ((unsigned)t.z) >> 16, e1 = t.w;

    u32x4 p0 = *(const u32x4*)(pq + (size_t)s0 * 512 + c0);
    u32x4 q0 = *(const u32x4*)(pq + (size_t)d0 * 512 + 256 + c0);
    u32x4 p1 = *(const u32x4*)(pq + (size_t)s1 * 512 + c0);
    u32x4 q1 = *(const u32x4*)(pq + (size_t)d1 * 512 + 256 + c0);

    float sum0 = 0.f, sum1 = 0.f;
    silu_dot2(p0, q0, w2r, sum0);
    silu_dot2(p1, q1, w2r, sum1);

#pragma unroll
    for (int off = 1; off < 32; off <<= 1) {
      sum0 += __shfl_xor(sum0, off, 64);
      sum1 += __shfl_xor(sum1, off, 64);
    }
    if (l == 0) {
      out[e0] = sum0 + bb;
      out[e1] = sum1 + bb;
    }
  }
}

// ---------------- unsorted edge kernel (fallback path; r3-structure) --------
__launch_bounds__(256, 8)
__global__ void k_edge_uns(const __bf16* __restrict__ pq,
                           const int*   __restrict__ ei,
                           const float* __restrict__ w2,
                           const float* __restrict__ b2,
                           float* __restrict__ out)
{
  const int tid  = threadIdx.x;
  const int lane = tid & 63;
  const int wid  = tid >> 6;
  const int half = lane >> 5;
  const int l    = lane & 31;
  const int c0   = l * 8;
  const float LN2 = 0.69314718f;

  float w2r[8];
  {
    float4 a = *(const float4*)(w2 + c0);
    float4 b = *(const float4*)(w2 + c0 + 4);
    w2r[0]=a.x*LN2; w2r[1]=a.y*LN2; w2r[2]=a.z*LN2; w2r[3]=a.w*LN2;
    w2r[4]=b.x*LN2; w2r[5]=b.y*LN2; w2r[6]=b.z*LN2; w2r[7]=b.w*LN2;
  }
  const float bb = b2[0];

  for (int e = blockIdx.x * 16 + (wid * 2 + half) * 2; e < E_EDGES; e += gridDim.x * 16) {
    int s0 = ei[e];     int d0 = ei[E_EDGES + e];
    int s1 = ei[e + 1]; int d1 = ei[E_EDGES + e + 1];

    u32x4 p0 = *(const u32x4*)(pq + (size_t)s0 * 512 + c0);
    u32x4 q0 = *(const u32x4*)(pq + (size_t)d0 * 512 + 256 + c0);
    u32x4 p1 = *(const u32x4*)(pq + (size_t)s1 * 512 + c0);
    u32x4 q1 = *(const u32x4*)(pq + (size_t)d1 * 512 + 256 + c0);

    float sum0 = 0.f, sum1 = 0.f;
    silu_dot2(p0, q0, w2r, sum0);
    silu_dot2(p1, q1, w2r, sum1);

#pragma unroll
    for (int off = 1; off < 32; off <<= 1) {
      sum0 += __shfl_xor(sum0, off, 64);
      sum1 += __shfl_xor(sum1, off, 64);
    }
    if (l == 0) *(float2*)(out + e) = make_float2(sum0 + bb, sum1 + bb);
  }
}

// ---------------- launch ----------------
extern "C" void kernel_launch(void* const* d_in, const int* in_sizes, int n_in,
                              void* d_out, int out_size, void* d_ws, size_t ws_size,
                              hipStream_t stream) {
  const float* instr = (const float*)d_in[0];
  const float* x     = (const float*)d_in[1];
  const int*   ei    = (const int*)d_in[2];
  const int*   batch = (const int*)d_in[3];
  const float* W1    = (const float*)d_in[4];
  const float* b1    = (const float*)d_in[5];
  const float* W2    = (const float*)d_in[6];
  const float* b2    = (const float*)d_in[7];
  float* out = (float*)d_out;
  char* ws = (char*)d_ws;

  // layout:
  //   [0, 131072)                 w1pt
  //   [131072, 196608)            r2
  //   [196608, 51,396,608)        pq
  //   [51,396,608, +200,000)      cnt    (sorted path)
  //   [51,596,608, +1,024)        pref
  //   [51,597,632, +6,400,000)    sde
  const size_t off_w1pt = 0;
  const size_t off_r2   = 131072;
  const size_t off_pq   = 196608;
  const size_t off_cnt  = 51396608;
  const size_t off_pref = 51596608;
  const size_t off_sde  = 51597632;
  const size_t need_full   = 51396608;
  const size_t need_sorted = 57997632;

  if (ws_size >= need_full) {
    __bf16* w1pt = (__bf16*)(ws + off_w1pt);
    float*  r2   = (float*)(ws + off_r2);
    __bf16* pq   = (__bf16*)(ws + off_pq);

    if (ws_size >= need_sorted) {
      int*  cnt  = (int*)(ws + off_cnt);
      int*  pref = (int*)(ws + off_pref);
      int2* sde  = (int2*)(ws + off_sde);

      hipMemsetAsync(ws + off_cnt, 0, N_NODES_C * sizeof(int), stream);
      k_prep<1><<<PREP_W1_BLKS + PREP_R2_BLKS + PREP_HIST_BLKS, 256, 0, stream>>>(
          W1, instr, b1, ei, w1pt, r2, cnt);
      k_scan1<<<CHUNKS, 256, 0, stream>>>(cnt, pref);
      k_scan2<<<1, 256, 0, stream>>>(pref);
      dim3 g1((N_NODES_C + 127) / 128, 3);   // y<2: GEMM slices; y==2: scatter
      k_nodegemm<<<g1, 512, 0, stream>>>(x, w1pt, batch, r2, pq, ei, cnt, pref, sde);
      k_edge2<<<2048, 256, 0, stream>>>(pq, sde, W2, b2, out);
    } else {
      k_prep<0><<<PREP_W1_BLKS + PREP_R2_BLKS, 256, 0, stream>>>(
          W1, instr, b1, ei, w1pt, r2, nullptr);
      dim3 g1((N_NODES_C + 127) / 128, 2);
      k_nodegemm<<<g1, 512, 0, stream>>>(x, w1pt, batch, r2, pq,
                                         nullptr, nullptr, nullptr, nullptr);
      k_edge_uns<<<2048, 256, 0, stream>>>(pq, ei, W2, b2, out);
    }
    return;
  }
}

// Round 10
// 147.928 us; speedup vs baseline: 1.3818x; 1.3818x over previous
//
#include <hip/hip_runtime.h>
#include <hip/hip_bf16.h>
#include <stdint.h>

#define E_EDGES   800000
#define N_NODES_C 50000
#define NG        64
#define DD        128     // NODE_DIM == INSTR_DIM
#define HH        256     // HIDDEN_DIM
#define KDIM      384     // 2*128 + 128

typedef __bf16 bf16x8 __attribute__((ext_vector_type(8)));
typedef __bf16 bf16x4 __attribute__((ext_vector_type(4)));
typedef float  f32x4  __attribute__((ext_vector_type(4)));
typedef uint32_t u32x4 __attribute__((ext_vector_type(4)));

__device__ __forceinline__ void gld16(const void* g, void* l) {
  __builtin_amdgcn_global_load_lds(
      (__attribute__((address_space(1))) void*)g,
      (__attribute__((address_space(3))) void*)l, 16, 0, 0);
}

__device__ __forceinline__ float bf_hi(uint32_t u) { return __uint_as_float(u & 0xffff0000u); }
__device__ __forceinline__ float bf_lo(uint32_t u) { return __uint_as_float(u << 16); }

// ---------------- prep kernel: w1pt transpose + r2 (r8-proven) ----------------
// blocks [0,256): w1pt[n][k] (512x128 bf16)   n<256: W1a^T ; n>=256: W1b^T
// blocks [256,320): r2[g][c] = instr[g] @ W1c + b1   (64 x 256 f32)
#define PREP_W1_BLKS  256
#define PREP_R2_BLKS  64

__global__ void k_prep(const float* __restrict__ w1, const float* __restrict__ instr,
                       const float* __restrict__ b1,
                       __bf16* __restrict__ w1pt, float* __restrict__ r2) {
  __shared__ float ins[DD];
  const int bid = blockIdx.x;
  const int tid = threadIdx.x;
  if (bid < PREP_W1_BLKS) {
    int idx = bid * 256 + tid;                 // 512*128 = 65536
    int n = idx >> 7;
    int k = idx & 127;
    float v = (n < 256) ? w1[k * HH + n] : w1[(128 + k) * HH + (n - 256)];
    w1pt[n * 128 + k] = (__bf16)v;
  } else {
    int g = bid - PREP_W1_BLKS;
    int c = tid;
    if (c < DD) ins[c] = instr[g * DD + c];
    __syncthreads();
    float sum = b1[c];
#pragma unroll 8
    for (int k = 0; k < DD; ++k) sum += ins[k] * w1[(256 + k) * HH + c];
    r2[g * HH + c] = sum;
  }
}

// ---------------- phase 1: node GEMM  PQ = x @ [W1a | W1b], P-half += r2 ----
// A staged directly from f32 x (reg-load + cvt + ds_write; r8-proven).
// Epilogue multiplies by log2(e): PQ holds v' = 1.4427*v so the edge phase
// computes exp2(-v') = e^-v directly; w2 is pre-multiplied by ln2 there.
__launch_bounds__(512, 4)
__global__ void k_nodegemm(const float* __restrict__ x,
                           const __bf16* __restrict__ w1pt,
                           const int*   __restrict__ batch,
                           const float* __restrict__ r2,
                           __bf16* __restrict__ pq)
{
  __shared__ __align__(16) char smem[16384 + 32768];
  char* As = smem;             // 2 x [128 rows][32k] bf16, swizzled 16B slots
  char* Bs = smem + 16384;     // 2 x [256 cols][32k] bf16

  const int tid  = threadIdx.x;
  const int lane = tid & 63;
  const int wid  = tid >> 6;
  const int rowbase = blockIdx.x * 128;
  const int nt      = blockIdx.y;          // 0/1 -> cols [0,256) / [256,512)

  const int arow  = tid >> 2;
  const int aslot = tid & 3;
  const int akap  = aslot ^ ((arow >> 1) & 3);
  int gr = rowbase + arow; if (gr >= N_NODES_C) gr = N_NODES_C - 1;
  const float* aptr = x + (size_t)gr * DD + akap * 8;

  const char* bptr[2];
#pragma unroll
  for (int it = 0; it < 2; ++it) {
    int j2 = tid + it * 512;
    int n  = j2 >> 2;
    int bk = (j2 & 3) ^ ((n >> 1) & 3);
    bptr[it] = (const char*)w1pt + (size_t)(nt * 256 + n) * 256 + bk * 16;
  }

  char* ldsB = Bs + wid * 1024;

  auto stage = [&](int cur, int kk) {
    gld16(bptr[0] + kk * 64, ldsB + cur * 16384);
    gld16(bptr[1] + kk * 64, ldsB + cur * 16384 + 8192);
    const float* gf = aptr + kk * 32;
    float4 v0 = *(const float4*)gf;
    float4 v1 = *(const float4*)(gf + 4);
    bf16x8 bv;
    bv[0] = (__bf16)v0.x; bv[1] = (__bf16)v0.y; bv[2] = (__bf16)v0.z; bv[3] = (__bf16)v0.w;
    bv[4] = (__bf16)v1.x; bv[5] = (__bf16)v1.y; bv[6] = (__bf16)v1.z; bv[7] = (__bf16)v1.w;
    *(bf16x8*)(As + cur * 8192 + tid * 16) = bv;
  };

  const int wm    = wid >> 2;
  const int wn    = wid & 3;
  const int l15   = lane & 15;
  const int kap_r = (lane >> 4) ^ ((l15 >> 1) & 3);
  const int aoff  = wm * 4096 + l15 * 64 + kap_r * 16;
  const int boff  = wn * 4096 + l15 * 64 + kap_r * 16;

  f32x4 acc[4][4];
#pragma unroll
  for (int mi = 0; mi < 4; ++mi)
#pragma unroll
    for (int ni = 0; ni < 4; ++ni)
      acc[mi][ni] = f32x4{0.f, 0.f, 0.f, 0.f};

  stage(0, 0);

  for (int kk = 0; kk < 4; ++kk) {
    const int cur = kk & 1;
    __syncthreads();
    if (kk + 1 < 4) stage(cur ^ 1, kk + 1);

    const char* pA = As + cur * 8192;
    const char* pB = Bs + cur * 16384;
    bf16x8 av[4], bv[4];
#pragma unroll
    for (int mi = 0; mi < 4; ++mi) av[mi] = *(const bf16x8*)(pA + aoff + mi * 1024);
#pragma unroll
    for (int ni = 0; ni < 4; ++ni) bv[ni] = *(const bf16x8*)(pB + boff + ni * 1024);
#pragma unroll
    for (int mi = 0; mi < 4; ++mi)
#pragma unroll
      for (int ni = 0; ni < 4; ++ni)
        acc[mi][ni] = __builtin_amdgcn_mfma_f32_16x16x32_bf16(av[mi], bv[ni], acc[mi][ni], 0, 0, 0);
  }

  const int rg = lane >> 4;
  const bool fold = (nt == 0);
  const float L2E = 1.44269504f;
#pragma unroll
  for (int mi = 0; mi < 4; ++mi) {
    int row = rowbase + wm * 64 + mi * 16 + rg * 4;
#pragma unroll
    for (int r = 0; r < 4; ++r) {
      int rr = row + r;
      if (rr < N_NODES_C) {
        float addv[4] = {0.f, 0.f, 0.f, 0.f};
        if (fold) {
          int g = batch[rr];
          const float* r2row = r2 + g * HH + wn * 64 + l15;
#pragma unroll
          for (int ni = 0; ni < 4; ++ni) addv[ni] = r2row[ni * 16];
        }
        size_t base = (size_t)rr * 512 + nt * 256 + wn * 64 + l15;
#pragma unroll
        for (int ni = 0; ni < 4; ++ni)
          pq[base + ni * 16] = (__bf16)((acc[mi][ni][r] + addv[ni]) * L2E);
      }
    }
  }
}

// ---------------- shared silu-dot core (PQ prescaled by log2e, w2 by ln2) ---
// Proven in r9's passing edge2 (absmax 0.00390625).
__device__ __forceinline__ void silu_dot2(const u32x4& p, const u32x4& q,
                                          const float* w2r, float& sum) {
#pragma unroll
  for (int k = 0; k < 4; ++k) {
    float va = bf_lo(p[k]) + bf_lo(q[k]);      // v' = 1.4427*v
    float vb = bf_hi(p[k]) + bf_hi(q[k]);
    float ta = __builtin_amdgcn_exp2f(-va);    // e^-v
    float tb = __builtin_amdgcn_exp2f(-vb);
    float da = 1.f + ta, db = 1.f + tb;
    float rc = __builtin_amdgcn_rcpf(da * db);
    sum += (va * w2r[2 * k]) * (rc * db) + (vb * w2r[2 * k + 1]) * (rc * da);
  }
}

// ---------------- phase 2: edge gather + silu + dot(w2) ----------------
// r3-proven shape (114.7 us): 32 lanes/edge, 8 cols/lane, 2 edges per
// lane-group per iteration, NO index prefetch, NO deeper unroll — both
// proven to inflate the concurrent L2 working set and regress (r5, r8).
__launch_bounds__(256, 8)
__global__ void k_edge(const __bf16* __restrict__ pq,
                       const int*   __restrict__ ei,
                       const float* __restrict__ w2,
                       const float* __restrict__ b2,
                       float* __restrict__ out)
{
  const int tid  = threadIdx.x;
  const int lane = tid & 63;
  const int wid  = tid >> 6;
  const int half = lane >> 5;
  const int l    = lane & 31;
  const int c0   = l * 8;
  const float LN2 = 0.69314718f;

  float w2r[8];
  {
    float4 a = *(const float4*)(w2 + c0);
    float4 b = *(const float4*)(w2 + c0 + 4);
    w2r[0]=a.x*LN2; w2r[1]=a.y*LN2; w2r[2]=a.z*LN2; w2r[3]=a.w*LN2;
    w2r[4]=b.x*LN2; w2r[5]=b.y*LN2; w2r[6]=b.z*LN2; w2r[7]=b.w*LN2;
  }
  const float bb = b2[0];

  for (int e = blockIdx.x * 16 + (wid * 2 + half) * 2; e < E_EDGES; e += gridDim.x * 16) {
    int s0 = ei[e];     int d0 = ei[E_EDGES + e];
    int s1 = ei[e + 1]; int d1 = ei[E_EDGES + e + 1];

    u32x4 p0 = *(const u32x4*)(pq + (size_t)s0 * 512 + c0);
    u32x4 q0 = *(const u32x4*)(pq + (size_t)d0 * 512 + 256 + c0);
    u32x4 p1 = *(const u32x4*)(pq + (size_t)s1 * 512 + c0);
    u32x4 q1 = *(const u32x4*)(pq + (size_t)d1 * 512 + 256 + c0);

    float sum0 = 0.f, sum1 = 0.f;
    silu_dot2(p0, q0, w2r, sum0);
    silu_dot2(p1, q1, w2r, sum1);

#pragma unroll
    for (int off = 1; off < 32; off <<= 1) {
      sum0 += __shfl_xor(sum0, off, 64);
      sum1 += __shfl_xor(sum1, off, 64);
    }
    if (l == 0) *(float2*)(out + e) = make_float2(sum0 + bb, sum1 + bb);
  }
}

// ================= small-ws fallback (round-1 proven, MODE 1) =================
#define BM 128
#define KSTEPS 12
#define THREADS 512

__global__ void k_w1t_fb(const float* __restrict__ w1, __bf16* __restrict__ w1t) {
  int idx = blockIdx.x * blockDim.x + threadIdx.x;
  if (idx < KDIM * HH) {
    int k = idx >> 8;
    int n = idx & 255;
    w1t[n * KDIM + k] = (__bf16)w1[idx];
  }
}

__launch_bounds__(THREADS, 4)
__global__ void k_main_fb(const float* __restrict__ xf,
                          const float* __restrict__ instrf,
                          const int*   __restrict__ ei,
                          const int*   __restrict__ batch,
                          const __bf16* __restrict__ w1t,
                          const float* __restrict__ b1,
                          const float* __restrict__ w2,
                          const float* __restrict__ b2,
                          float* __restrict__ out)
{
  __shared__ __align__(16) char smem[16384 + 32768 + 2048];
  char*  As  = smem;
  char*  Bs  = smem + 16384;
  float* red = (float*)(smem + 16384 + 32768);

  const int tid  = threadIdx.x;
  const int lane = tid & 63;
  const int wid  = tid >> 6;
  const int blk  = blockIdx.x;

  const int arow  = tid >> 2;
  const int aslot = tid & 3;
  const int akap  = aslot ^ ((arow >> 1) & 3);
  const int e     = blk * BM + arow;
  const int s     = ei[e];
  const int d     = ei[E_EDGES + e];
  const int g     = batch[s];

  const float* fS = xf     + s * DD + akap * 8;
  const float* fD = xf     + d * DD + akap * 8;
  const float* fI = instrf + g * DD + akap * 8;

  const char* bptr[2];
#pragma unroll
  for (int it = 0; it < 2; ++it) {
    int j2 = tid + it * 512;
    int n  = j2 >> 2;
    int bk = (j2 & 3) ^ ((n >> 1) & 3);
    bptr[it] = (const char*)w1t + n * (KDIM * 2) + bk * 16;
  }

  char* ldsB = Bs + wid * 1024;

  auto stage = [&](int cur, int kk) {
    gld16(bptr[0] + kk * 64, ldsB + cur * 16384);
    gld16(bptr[1] + kk * 64, ldsB + cur * 16384 + 8192);
    const float* gf = (kk < 4) ? (fS + kk * 32)
                    : (kk < 8) ? (fD + (kk - 4) * 32)
                               : (fI + (kk - 8) * 32);
    float4 v0 = *(const float4*)gf;
    float4 v1 = *(const float4*)(gf + 4);
    bf16x8 bv;
    bv[0] = (__bf16)v0.x; bv[1] = (__bf16)v0.y; bv[2] = (__bf16)v0.z; bv[3] = (__bf16)v0.w;
    bv[4] = (__bf16)v1.x; bv[5] = (__bf16)v1.y; bv[6] = (__bf16)v1.z; bv[7] = (__bf16)v1.w;
    *(bf16x8*)(As + cur * 8192 + tid * 16) = bv;
  };

  const int wm    = wid >> 2;
  const int wn    = wid & 3;
  const int l15   = lane & 15;
  const int kap_r = (lane >> 4) ^ ((l15 >> 1) & 3);
  const int aoff  = wm * 4096 + l15 * 64 + kap_r * 16;
  const int boff  = wn * 4096 + l15 * 64 + kap_r * 16;

  f32x4 acc[4][4];
#pragma unroll
  for (int mi = 0; mi < 4; ++mi)
#pragma unroll
    for (int ni = 0; ni < 4; ++ni)
      acc[mi][ni] = f32x4{0.f, 0.f, 0.f, 0.f};

  stage(0, 0);

  for (int kk = 0; kk < KSTEPS; ++kk) {
    const int cur = kk & 1;
    __syncthreads();
    if (kk + 1 < KSTEPS) stage(cur ^ 1, kk + 1);

    const char* pA = As + cur * 8192;
    const char* pB = Bs + cur * 16384;
    bf16x8 av[4], bv[4];
#pragma unroll
    for (int mi = 0; mi < 4; ++mi) av[mi] = *(const bf16x8*)(pA + aoff + mi * 1024);
#pragma unroll
    for (int ni = 0; ni < 4; ++ni) bv[ni] = *(const bf16x8*)(pB + boff + ni * 1024);
#pragma unroll
    for (int mi = 0; mi < 4; ++mi)
#pragma unroll
      for (int ni = 0; ni < 4; ++ni)
        acc[mi][ni] = __builtin_amdgcn_mfma_f32_16x16x32_bf16(av[mi], bv[ni], acc[mi][ni], 0, 0, 0);
  }

  float b1c[4], w2c[4];
#pragma unroll
  for (int ni = 0; ni < 4; ++ni) {
    int n = wn * 64 + ni * 16 + l15;
    b1c[ni] = b1[n];
    w2c[ni] = w2[n];
  }

  float rowsum[4][4];
#pragma unroll
  for (int mi = 0; mi < 4; ++mi)
#pragma unroll
    for (int r = 0; r < 4; ++r) rowsum[mi][r] = 0.f;

#pragma unroll
  for (int ni = 0; ni < 4; ++ni) {
    float bbv = b1c[ni], ww = w2c[ni];
#pragma unroll
    for (int mi = 0; mi < 4; ++mi)
#pragma unroll
      for (int r = 0; r < 4; ++r) {
        float v  = acc[mi][ni][r] + bbv;
        float sv = v / (1.0f + __expf(-v));
        rowsum[mi][r] += sv * ww;
      }
  }

#pragma unroll
  for (int off = 1; off < 16; off <<= 1)
#pragma unroll
    for (int mi = 0; mi < 4; ++mi)
#pragma unroll
      for (int r = 0; r < 4; ++r)
        rowsum[mi][r] += __shfl_xor(rowsum[mi][r], off, 64);

  if (l15 == 0) {
    int rg = lane >> 4;
#pragma unroll
    for (int mi = 0; mi < 4; ++mi)
#pragma unroll
      for (int r = 0; r < 4; ++r)
        red[wn * 128 + wm * 64 + mi * 16 + rg * 4 + r] = rowsum[mi][r];
  }
  __syncthreads();

  if (tid < BM) {
    float v = red[tid] + red[128 + tid] + red[256 + tid] + red[384 + tid] + b2[0];
    out[blk * BM + tid] = v;
  }
}

// ---------------- launch ----------------
extern "C" void kernel_launch(void* const* d_in, const int* in_sizes, int n_in,
                              void* d_out, int out_size, void* d_ws, size_t ws_size,
                              hipStream_t stream) {
  const float* instr = (const float*)d_in[0];
  const float* x     = (const float*)d_in[1];
  const int*   ei    = (const int*)d_in[2];
  const int*   batch = (const int*)d_in[3];
  const float* W1    = (const float*)d_in[4];
  const float* b1    = (const float*)d_in[5];
  const float* W2    = (const float*)d_in[6];
  const float* b2    = (const float*)d_in[7];
  float* out = (float*)d_out;
  char* ws = (char*)d_ws;

  // layout:
  //   [0, 131072)            w1pt
  //   [131072, 196608)       r2
  //   [196608, 51,396,608)   pq
  const size_t off_w1pt = 0;
  const size_t off_r2   = 131072;
  const size_t off_pq   = 196608;
  const size_t need_full = 51396608;

  if (ws_size >= need_full) {
    __bf16* w1pt = (__bf16*)(ws + off_w1pt);
    float*  r2   = (float*)(ws + off_r2);
    __bf16* pq   = (__bf16*)(ws + off_pq);

    k_prep<<<PREP_W1_BLKS + PREP_R2_BLKS, 256, 0, stream>>>(W1, instr, b1, w1pt, r2);
    dim3 g1((N_NODES_C + 127) / 128, 2);
    k_nodegemm<<<g1, 512, 0, stream>>>(x, w1pt, batch, r2, pq);
    k_edge<<<2048, 256, 0, stream>>>(pq, ei, W2, b2, out);
    return;
  }

  // tiny-ws fallback: round-1 fused edge GEMM (needs only 196,608 B)
  __bf16* w1t = (__bf16*)ws;
  k_w1t_fb<<<(KDIM * HH + 255) / 256, 256, 0, stream>>>(W1, w1t);
  k_main_fb<<<E_EDGES / BM, THREADS, 0, stream>>>(x, instr, ei, batch, w1t,
                                                  b1, W2, b2, out);
}